// Round 19
// baseline (356.356 us; speedup 1.0000x reference)
//
#include <hip/hip_runtime.h>
#include <math.h>

#define NB 64
#define NN 207
#define NT 48
#define NF 6
#define NH 64
#define NSEQ (NB*NN)        // 13248 = 828*16
#define NG   (NSEQ/16)      // 828 LSTM blocks of 16 seqs
#define TSU  ((size_t)NSEQ*NH)   // ushorts per t-plane of sxh/sxl

typedef short bf8_t __attribute__((ext_vector_type(8)));
typedef float f4_t  __attribute__((ext_vector_type(4)));
typedef unsigned short ushort;
typedef unsigned int uint;

__device__ __forceinline__ ushort bf16h(float x){
  uint u = __float_as_uint(x);
  return (ushort)((u + 0x7FFF + ((u>>16)&1)) >> 16);
}
__device__ __forceinline__ float bf16f(ushort h){
  return __uint_as_float((uint)h << 16);
}
__device__ __forceinline__ float fsig(float x){
  return __builtin_amdgcn_rcpf(1.0f + __expf(-x));
}
__device__ __forceinline__ float ftanh(float x){
  x = fminf(15.0f, fmaxf(-15.0f, x));
  float e = __expf(2.0f*x);
  return 1.0f - 2.0f*__builtin_amdgcn_rcpf(e + 1.0f);
}

// interchange: sxh/sxl[t][seq][64] bf16 hi/lo planes (row-major == LSTM A-frag order)

// ---------------- GCN v9: 2 t-planes per block -> 3 blocks/CU ----------------
// gcn7 structure (scattered-store epilogue restored — r18 proved coalescing
// neutral) with the 6-t x-stage cut to 2-t: LDS 66.8 -> 43 KB so THREE blocks
// co-reside per CU (1536 blocks = exactly 2 rounds at 3/CU). More cross-block
// overlap to hide the barrier skew that dominates GCN's stall time.
#define HW 72
#define XS2 12
#define GCN9_LDS_BYTES (208*HW*2 + (207*XS2 + NF*64 + 64 + 64 + 2*64 + 2*64 + 16)*4)

__global__ __launch_bounds__(256, 3) void gcn_kernel(
    const float* __restrict__ x, const float* __restrict__ W1, const float* __restrict__ b1,
    const float* __restrict__ W2, const float* __restrict__ b2,
    ushort* __restrict__ sxh, ushort* __restrict__ sxl)
{
  extern __shared__ char smraw[];
  ushort* h1b = (ushort*)smraw;            // [208][72] bf16 (row 207 = zero pad)
  float*  xs2 = (float*)(h1b + 208*HW);    // [207][12]
  float*  W1s = xs2 + 207*XS2;             // [6][64]
  float*  b1s = W1s + NF*64;               // 64
  float*  b2s = b1s + 64;                  // 64
  float*  S2_ = b2s + 64;                  // [2][64]
  float*  r1_ = S2_ + 2*64;                // [2][64]
  float*  xsA = r1_ + 2*64;                // [2][8]

  const int tid = threadIdx.x;
  const int tg = blockIdx.x, b = blockIdx.y;
  const float inv = 1.0f/208.0f;
  const int l = tid & 63;
  const int w = __builtin_amdgcn_readfirstlane(tid >> 6);
  const int col = l & 15, q = l >> 4;
  const int cw = w*16 + col;

  for (int i=tid; i<2*64; i+=256){ S2_[i]=0.f; r1_[i]=0.f; }
  if (tid < 16) xsA[tid] = 0.f;
  if (tid < 72) h1b[207*HW + tid] = 0;

  for (int i=tid;i<NF*64;i+=256) W1s[i]=W1[i];
  if (tid<64){ b1s[tid]=b1[tid]; b2s[tid]=b2[tid]; }
  {
    const float* xb = x + (size_t)b*NN*(NT*NF) + (size_t)tg*12;
    for (int i=tid; i<207*3; i+=256){
      int n = i/3, c = (i - n*3)*4;
      *(float4*)&xs2[n*XS2 + c] = *(const float4*)&xb[(size_t)n*(NT*NF) + c];
    }
  }
  __syncthreads();

  // xsA[tt][f] = sum_n x: 96 threads, 8 partials each
  if (tid < 96){
    int tt = tid/48, rem = tid - tt*48, f = rem>>3, p = rem&7;
    float ps = 0.f;
    for (int n=p; n<NN; n+=8) ps += xs2[n*XS2 + tt*6 + f];
    atomicAdd(&xsA[tt*8+f], ps);
  }

  // W2 B-fragments (loaded once for both t)
  float wtmp[16];
  #pragma unroll
  for (int kc=0;kc<2;kc++)
    #pragma unroll
    for (int j=0;j<8;j++)
      wtmp[kc*8+j] = W2[(size_t)(kc*32 + q*8 + j)*64 + cw];
  bf8_t B2[2];
  #pragma unroll
  for (int kc=0;kc<2;kc++){
    bf8_t ph;
    #pragma unroll
    for (int j=0;j<8;j++) ph[j] = (short)bf16h(wtmp[kc*8+j]);
    B2[kc]=ph;
  }
  __syncthreads();

  const int ht4 = (tid & 15) * 4;
  const int nti = tid >> 4;

  #pragma unroll 1
  for (int tt=0; tt<2; tt++){
    const int t = tg*2 + tt;
    // ---- layer 1: h1 = relu((x@W1 + S1)/208 + b1) -> bf16 plane + r1 ----
    {
      float s1v[4];
      #pragma unroll
      for (int j=0;j<4;j++){
        float a = 0.f;
        #pragma unroll
        for (int f=0;f<NF;f++) a += xsA[tt*8+f]*W1s[f*64 + ht4 + j];
        s1v[j] = a;
      }
      float cs0=0.f, cs1=0.f, cs2=0.f, cs3=0.f;
      #pragma unroll 1
      for (int p=0;p<4;p++){
        int nt = p*16 + nti;
        if (nt < 52){
          #pragma unroll
          for (int i=0;i<4;i++){
            int n = 4*nt+i;
            if (n < NN){
              float a0=0.f,a1=0.f,a2=0.f,a3=0.f;
              #pragma unroll
              for (int f=0;f<NF;f++){
                float xv = xs2[n*XS2 + tt*6 + f];
                float4 wv = *(const float4*)&W1s[f*64 + ht4];
                a0+=xv*wv.x; a1+=xv*wv.y; a2+=xv*wv.z; a3+=xv*wv.w;
              }
              float v0=(a0+s1v[0])*inv + b1s[ht4+0]; v0 = v0>0.f?v0:0.f;
              float v1=(a1+s1v[1])*inv + b1s[ht4+1]; v1 = v1>0.f?v1:0.f;
              float v2=(a2+s1v[2])*inv + b1s[ht4+2]; v2 = v2>0.f?v2:0.f;
              float v3=(a3+s1v[3])*inv + b1s[ht4+3]; v3 = v3>0.f?v3:0.f;
              ushort4 hi;
              hi.x=bf16h(v0); hi.y=bf16h(v1); hi.z=bf16h(v2); hi.w=bf16h(v3);
              *(ushort4*)&h1b[n*HW + ht4] = hi;
              cs0+=v0; cs1+=v1; cs2+=v2; cs3+=v3;
            }
          }
        }
      }
      atomicAdd(&r1_[tt*64+ht4+0], cs0);
      atomicAdd(&r1_[tt*64+ht4+1], cs1);
      atomicAdd(&r1_[tt*64+ht4+2], cs2);
      atomicAdd(&r1_[tt*64+ht4+3], cs3);
    }
    __syncthreads();

    // ---- S2 = r1 @ W2 (fp32 exact) ----
    {
      int h = tid & 63, pp = tid >> 6;
      float ps = 0.f;
      #pragma unroll
      for (int k=0;k<16;k++) ps += r1_[tt*64+pp*16+k]*W2[(size_t)(pp*16+k)*64 + h];
      atomicAdd(&S2_[tt*64+h], ps);
    }

    // ---- layer 2: single-bf16 MFMA ----
    f4_t acc[13];
    #pragma unroll
    for (int mt=0;mt<13;mt++){ f4_t z; z[0]=0.f;z[1]=0.f;z[2]=0.f;z[3]=0.f; acc[mt]=z; }
    #pragma unroll 2
    for (int mt=0;mt<13;mt++){
      #pragma unroll
      for (int kc=0;kc<2;kc++){
        bf8_t ah = *(const bf8_t*)(h1b + (mt*16+col)*HW + kc*32 + q*8);
        acc[mt] = __builtin_amdgcn_mfma_f32_16x16x32_bf16(ah, B2[kc], acc[mt], 0,0,0);
      }
    }
    __syncthreads();   // S2 atomics + all h1 reads complete (h1b free for tt+1)

    // ---- epilogue: h2 split-bf16 -> hi/lo planes at [t][b*207+n][cw] ----
    {
      const float s2v = S2_[tt*64+cw], b2v = b2s[cw];
      const size_t obase = (size_t)t*TSU + (size_t)(b*NN)*NH + cw;
      #pragma unroll
      for (int mt=0;mt<13;mt++){
        #pragma unroll
        for (int r=0;r<4;r++){
          int n = mt*16 + q*4 + r;
          if (n < NN){
            float v = (acc[mt][r] + s2v)*inv + b2v;
            v = v>0.f ? v : 0.f;
            ushort hb = bf16h(v);
            sxh[obase + (size_t)n*NH] = hb;
            sxl[obase + (size_t)n*NH] = bf16h(v - bf16f(hb));
          }
        }
      }
    }
  }
}

// ---------------- LSTM v15 (unchanged from r17, session-best 203 us) ----------------
// lstm12 structure (zero-unpack x hi/lo planes, depth-2 prefetch, packed-u32 h)
// at launch_bounds(256,2): mild spill accepted to keep 2 blocks/CU co-resident.
#define HS 68

__global__ __launch_bounds__(256, 2) void lstm15_kernel(
    const ushort* __restrict__ sxh, const ushort* __restrict__ sxl,
    const float* __restrict__ Wih, const float* __restrict__ Whh,
    const float* __restrict__ bih, const float* __restrict__ bhh,
    const float* __restrict__ Wfc, const float* __restrict__ bfc, float* __restrict__ out)
{
  __shared__ uint hf[2][16*HS + 4];    // 8.7 KB

  const int tid = threadIdx.x;
  const int l = tid & 63;
  const int w = __builtin_amdgcn_readfirstlane(tid >> 6);
  const int col = l & 15, q = l >> 4;
  const int g = blockIdx.x;

  // B fragments: [ty][mat*2+kk]; mat 0 = Wih (x), 1 = Whh (h). 128 VGPRs.
  bf8_t Bh[4][4], Bl[4][4];
  #pragma unroll
  for (int mat=0; mat<2; mat++){
    const float* W = mat ? Whh : Wih;
    #pragma unroll
    for (int ty=0; ty<4; ty++){
      #pragma unroll
      for (int kk=0; kk<2; kk++){
        const float* wp = W + (size_t)(ty*64 + w*16 + col)*64 + kk*32 + q*8;
        bf8_t ph, pl;
        #pragma unroll
        for (int j=0;j<8;j++){
          float wv = wp[j];
          ushort hb = bf16h(wv);
          ph[j] = (short)hb;
          pl[j] = (short)bf16h(wv - bf16f(hb));
        }
        Bh[ty][mat*2+kk] = ph;
        Bl[ty][mat*2+kk] = pl;
      }
    }
  }
  float bias[4];
  #pragma unroll
  for (int ty=0;ty<4;ty++){
    int r = ty*64 + w*16 + col;
    bias[ty] = bih[r] + bhh[r];
  }
  float c[4];
  #pragma unroll
  for (int i=0;i<4;i++) c[i]=0.f;

  for (int i=tid; i<16*HS; i+=256) hf[0][i] = 0;

  // x source: lane (col,q) reads 8 consecutive bf16 at row col, k = kk*32+q*8
  const ushort* xgh = sxh + (size_t)g*1024 + (size_t)(col*64 + q*8);
  const ushort* xgl = sxl + (size_t)g*1024 + (size_t)(col*64 + q*8);

  // depth-2 prefetch ring: slot (t&1) holds x(t)
  bf8_t pxh[2][2], pxl[2][2];
  #pragma unroll
  for (int s2=0; s2<2; s2++){
    const size_t off = (size_t)s2*TSU;
    pxh[s2][0] = *(const bf8_t*)(xgh + off);
    pxh[s2][1] = *(const bf8_t*)(xgh + off + 32);
    pxl[s2][0] = *(const bf8_t*)(xgl + off);
    pxl[s2][1] = *(const bf8_t*)(xgl + off + 32);
  }

  const int d = w*16 + col;
  const uint* hrd = &hf[0][0] + col*HS + q*8;
  __syncthreads();

  #pragma unroll 2
  for (int t=0; t<NT; t++){
    const int cur = t & 1;
    bf8_t cxh0 = pxh[cur][0], cxh1 = pxh[cur][1];
    bf8_t cxl0 = pxl[cur][0], cxl1 = pxl[cur][1];
    if (t+2 < NT){
      const size_t off = (size_t)(t+2)*TSU;
      pxh[cur][0] = *(const bf8_t*)(xgh + off);
      pxh[cur][1] = *(const bf8_t*)(xgh + off + 32);
      pxl[cur][0] = *(const bf8_t*)(xgl + off);
      pxl[cur][1] = *(const bf8_t*)(xgl + off + 32);
    }

    bf8_t hh[2], hl[2];
    {
      const uint* hb = hrd + (cur ? (16*HS+4) : 0);
      uint4 h0 = *(const uint4*)(hb);
      uint4 h1 = *(const uint4*)(hb + 4);
      uint4 h2 = *(const uint4*)(hb + 32);
      uint4 h3 = *(const uint4*)(hb + 36);
      uint u[8];
      u[0]=h0.x;u[1]=h0.y;u[2]=h0.z;u[3]=h0.w;u[4]=h1.x;u[5]=h1.y;u[6]=h1.z;u[7]=h1.w;
      #pragma unroll
      for (int j=0;j<8;j++){ hh[0][j]=(short)(u[j]>>16); hl[0][j]=(short)(u[j]&0xffff); }
      u[0]=h2.x;u[1]=h2.y;u[2]=h2.z;u[3]=h2.w;u[4]=h3.x;u[5]=h3.y;u[6]=h3.z;u[7]=h3.w;
      #pragma unroll
      for (int j=0;j<8;j++){ hh[1][j]=(short)(u[j]>>16); hl[1][j]=(short)(u[j]&0xffff); }
    }

    f4_t acc[4];
    #pragma unroll
    for (int ty=0;ty<4;ty++){ f4_t z; z[0]=bias[ty];z[1]=bias[ty];z[2]=bias[ty];z[3]=bias[ty]; acc[ty]=z; }
    #pragma unroll
    for (int ty=0;ty<4;ty++){
      acc[ty] = __builtin_amdgcn_mfma_f32_16x16x32_bf16(cxh0,  Bh[ty][0], acc[ty], 0,0,0);
      acc[ty] = __builtin_amdgcn_mfma_f32_16x16x32_bf16(cxl0,  Bh[ty][0], acc[ty], 0,0,0);
      acc[ty] = __builtin_amdgcn_mfma_f32_16x16x32_bf16(cxh0,  Bl[ty][0], acc[ty], 0,0,0);
      acc[ty] = __builtin_amdgcn_mfma_f32_16x16x32_bf16(cxh1,  Bh[ty][1], acc[ty], 0,0,0);
      acc[ty] = __builtin_amdgcn_mfma_f32_16x16x32_bf16(cxl1,  Bh[ty][1], acc[ty], 0,0,0);
      acc[ty] = __builtin_amdgcn_mfma_f32_16x16x32_bf16(cxh1,  Bl[ty][1], acc[ty], 0,0,0);
      acc[ty] = __builtin_amdgcn_mfma_f32_16x16x32_bf16(hh[0], Bh[ty][2], acc[ty], 0,0,0);
      acc[ty] = __builtin_amdgcn_mfma_f32_16x16x32_bf16(hl[0], Bh[ty][2], acc[ty], 0,0,0);
      acc[ty] = __builtin_amdgcn_mfma_f32_16x16x32_bf16(hh[0], Bl[ty][2], acc[ty], 0,0,0);
      acc[ty] = __builtin_amdgcn_mfma_f32_16x16x32_bf16(hh[1], Bh[ty][3], acc[ty], 0,0,0);
      acc[ty] = __builtin_amdgcn_mfma_f32_16x16x32_bf16(hl[1], Bh[ty][3], acc[ty], 0,0,0);
      acc[ty] = __builtin_amdgcn_mfma_f32_16x16x32_bf16(hh[1], Bl[ty][3], acc[ty], 0,0,0);
    }

    {
      uint* hw = &hf[cur^1][0];
      #pragma unroll
      for (int r=0;r<4;r++){
        float ig = fsig(acc[0][r]);
        float fg = fsig(acc[1][r]);
        float gt = ftanh(acc[2][r]);
        float og = fsig(acc[3][r]);
        float cc = fg*c[r] + ig*gt;
        c[r] = cc;
        float hv = og*ftanh(cc);
        int off = (q*4+r)*HS + d;
        if (t != NT-1){
          ushort hb2 = bf16h(hv);
          ushort lb2 = bf16h(hv - bf16f(hb2));
          hw[off] = ((uint)hb2<<16) | (uint)lb2;
        } else {
          hw[off] = __float_as_uint(hv);
        }
      }
    }
    __syncthreads();
  }

  if (tid < 16){
    float a = bfc[0];
    const uint* hT = &hf[NT&1][0];
    #pragma unroll 8
    for (int k=0;k<64;k++) a += __uint_as_float(hT[tid*HS + k]) * Wfc[k];
    out[g*16 + tid] = a;
  }
}

extern "C" void kernel_launch(void* const* d_in, const int* in_sizes, int n_in,
                              void* d_out, int out_size, void* d_ws, size_t ws_size,
                              hipStream_t stream) {
  const float* x   = (const float*)d_in[0];
  // d_in[1], d_in[2] (N1, N2): structurally dead — sigmoid(N1@N2)>0 is all-ones.
  const float* W1  = (const float*)d_in[3];
  const float* b1  = (const float*)d_in[4];
  const float* W2  = (const float*)d_in[5];
  const float* b2  = (const float*)d_in[6];
  const float* Wih = (const float*)d_in[7];
  const float* Whh = (const float*)d_in[8];
  const float* bih = (const float*)d_in[9];
  const float* bhh = (const float*)d_in[10];
  const float* Wfc = (const float*)d_in[11];
  const float* bfc = (const float*)d_in[12];

  ushort* sxh = (ushort*)d_ws;                 // [48][13248][64] bf16 hi (81.4 MB)
  ushort* sxl = sxh + (size_t)NT*TSU;          // [48][13248][64] bf16 lo (81.4 MB)
  float*  out = (float*)d_out;

  hipFuncSetAttribute((const void*)gcn_kernel, hipFuncAttributeMaxDynamicSharedMemorySize, GCN9_LDS_BYTES);

  gcn_kernel<<<dim3(NT/2, NB), 256, GCN9_LDS_BYTES, stream>>>(x, W1, b1, W2, b2, sxh, sxl);
  lstm15_kernel<<<NG, 256, 0, stream>>>(sxh, sxl, Wih, Whh, bih, bhh, Wfc, bfc, out);
}

// Round 20
// 334.484 us; speedup vs baseline: 1.0654x; 1.0654x over previous
//
#include <hip/hip_runtime.h>
#include <math.h>

#define NB 64
#define NN 207
#define NT 48
#define NF 6
#define NH 64
#define NSEQ (NB*NN)        // 13248 = 828*16
#define NG   (NSEQ/16)      // 828 LSTM blocks of 16 seqs
#define TSU  ((size_t)NSEQ*NH)   // ushorts per t-plane of sxh/sxl

typedef short bf8_t __attribute__((ext_vector_type(8)));
typedef float f4_t  __attribute__((ext_vector_type(4)));
typedef unsigned short ushort;
typedef unsigned int uint;

__device__ __forceinline__ ushort bf16h(float x){
  uint u = __float_as_uint(x);
  return (ushort)((u + 0x7FFF + ((u>>16)&1)) >> 16);
}
__device__ __forceinline__ float bf16f(ushort h){
  return __uint_as_float((uint)h << 16);
}
__device__ __forceinline__ float fsig(float x){
  return __builtin_amdgcn_rcpf(1.0f + __expf(-x));
}
__device__ __forceinline__ float ftanh(float x){
  x = fminf(15.0f, fmaxf(-15.0f, x));
  float e = __expf(2.0f*x);
  return 1.0f - 2.0f*__builtin_amdgcn_rcpf(e + 1.0f);
}

// interchange: sxh/sxl[t][seq][64] bf16 hi/lo planes (row-major == LSTM A-frag order)

// ---------------- GCN v7 (r17 best, ~131 us): 6 t-planes per block, 2/CU ----------------
#define HW 72
#define XS6 40
#define GCN7_LDS_BYTES (208*HW*2 + (207*XS6 + NF*64 + 64 + 64 + 6*64 + 6*64 + 48)*4)

__global__ __launch_bounds__(256, 2) void gcn_kernel(
    const float* __restrict__ x, const float* __restrict__ W1, const float* __restrict__ b1,
    const float* __restrict__ W2, const float* __restrict__ b2,
    ushort* __restrict__ sxh, ushort* __restrict__ sxl)
{
  extern __shared__ char smraw[];
  ushort* h1b = (ushort*)smraw;            // [208][72] bf16 (row 207 = zero pad)
  float*  xs6 = (float*)(h1b + 208*HW);    // [207][40]
  float*  W1s = xs6 + 207*XS6;             // [6][64]
  float*  b1s = W1s + NF*64;
  float*  b2s = b1s + 64;
  float*  S2_ = b2s + 64;                  // [6][64]
  float*  r1_ = S2_ + 6*64;                // [6][64]
  float*  xsA = r1_ + 6*64;                // [6][8]

  const int tid = threadIdx.x;
  const int tg = blockIdx.x, b = blockIdx.y;
  const float inv = 1.0f/208.0f;
  const int l = tid & 63;
  const int w = __builtin_amdgcn_readfirstlane(tid >> 6);
  const int col = l & 15, q = l >> 4;
  const int cw = w*16 + col;

  for (int i=tid; i<6*64; i+=256){ S2_[i]=0.f; r1_[i]=0.f; }
  if (tid < 48) xsA[tid] = 0.f;
  if (tid < 72) h1b[207*HW + tid] = 0;

  for (int i=tid;i<NF*64;i+=256) W1s[i]=W1[i];
  if (tid<64){ b1s[tid]=b1[tid]; b2s[tid]=b2[tid]; }
  {
    const float* xb = x + (size_t)b*NN*(NT*NF) + (size_t)tg*36;
    for (int i=tid; i<207*9; i+=256){
      int n = i/9, c = (i - n*9)*4;
      *(float4*)&xs6[n*XS6 + c] = *(const float4*)&xb[(size_t)n*(NT*NF) + c];
    }
  }
  __syncthreads();

  if (tid < 144){
    int tt = tid/24, rem = tid - tt*24, f = rem>>2, p = rem&3;
    float ps = 0.f;
    for (int n=p; n<NN; n+=4) ps += xs6[n*XS6 + tt*6 + f];
    atomicAdd(&xsA[tt*8+f], ps);
  }

  float wtmp[16];
  #pragma unroll
  for (int kc=0;kc<2;kc++)
    #pragma unroll
    for (int j=0;j<8;j++)
      wtmp[kc*8+j] = W2[(size_t)(kc*32 + q*8 + j)*64 + cw];
  bf8_t B2[2];
  #pragma unroll
  for (int kc=0;kc<2;kc++){
    bf8_t ph;
    #pragma unroll
    for (int j=0;j<8;j++) ph[j] = (short)bf16h(wtmp[kc*8+j]);
    B2[kc]=ph;
  }
  __syncthreads();

  const int ht4 = (tid & 15) * 4;
  const int nti = tid >> 4;

  #pragma unroll 1
  for (int tt=0; tt<6; tt++){
    const int t = tg*6 + tt;
    // ---- layer 1: h1 = relu((x@W1 + S1)/208 + b1) -> bf16 plane + r1 ----
    {
      float s1v[4];
      #pragma unroll
      for (int j=0;j<4;j++){
        float a = 0.f;
        #pragma unroll
        for (int f=0;f<NF;f++) a += xsA[tt*8+f]*W1s[f*64 + ht4 + j];
        s1v[j] = a;
      }
      float cs0=0.f, cs1=0.f, cs2=0.f, cs3=0.f;
      #pragma unroll 1
      for (int p=0;p<4;p++){
        int nt = p*16 + nti;
        if (nt < 52){
          #pragma unroll
          for (int i=0;i<4;i++){
            int n = 4*nt+i;
            if (n < NN){
              float a0=0.f,a1=0.f,a2=0.f,a3=0.f;
              #pragma unroll
              for (int f=0;f<NF;f++){
                float xv = xs6[n*XS6 + tt*6 + f];
                float4 wv = *(const float4*)&W1s[f*64 + ht4];
                a0+=xv*wv.x; a1+=xv*wv.y; a2+=xv*wv.z; a3+=xv*wv.w;
              }
              float v0=(a0+s1v[0])*inv + b1s[ht4+0]; v0 = v0>0.f?v0:0.f;
              float v1=(a1+s1v[1])*inv + b1s[ht4+1]; v1 = v1>0.f?v1:0.f;
              float v2=(a2+s1v[2])*inv + b1s[ht4+2]; v2 = v2>0.f?v2:0.f;
              float v3=(a3+s1v[3])*inv + b1s[ht4+3]; v3 = v3>0.f?v3:0.f;
              ushort4 hi;
              hi.x=bf16h(v0); hi.y=bf16h(v1); hi.z=bf16h(v2); hi.w=bf16h(v3);
              *(ushort4*)&h1b[n*HW + ht4] = hi;
              cs0+=v0; cs1+=v1; cs2+=v2; cs3+=v3;
            }
          }
        }
      }
      atomicAdd(&r1_[tt*64+ht4+0], cs0);
      atomicAdd(&r1_[tt*64+ht4+1], cs1);
      atomicAdd(&r1_[tt*64+ht4+2], cs2);
      atomicAdd(&r1_[tt*64+ht4+3], cs3);
    }
    __syncthreads();

    // ---- S2 = r1 @ W2 (fp32 exact) ----
    {
      int h = tid & 63, pp = tid >> 6;
      float ps = 0.f;
      #pragma unroll
      for (int k=0;k<16;k++) ps += r1_[tt*64+pp*16+k]*W2[(size_t)(pp*16+k)*64 + h];
      atomicAdd(&S2_[tt*64+h], ps);
    }

    // ---- layer 2: single-bf16 MFMA ----
    f4_t acc[13];
    #pragma unroll
    for (int mt=0;mt<13;mt++){ f4_t z; z[0]=0.f;z[1]=0.f;z[2]=0.f;z[3]=0.f; acc[mt]=z; }
    #pragma unroll 2
    for (int mt=0;mt<13;mt++){
      #pragma unroll
      for (int kc=0;kc<2;kc++){
        bf8_t ah = *(const bf8_t*)(h1b + (mt*16+col)*HW + kc*32 + q*8);
        acc[mt] = __builtin_amdgcn_mfma_f32_16x16x32_bf16(ah, B2[kc], acc[mt], 0,0,0);
      }
    }
    __syncthreads();   // S2 atomics + all h1 reads complete (h1b free for tt+1)

    // ---- epilogue: h2 split-bf16 -> hi/lo planes at [t][b*207+n][cw] ----
    {
      const float s2v = S2_[tt*64+cw], b2v = b2s[cw];
      const size_t obase = (size_t)t*TSU + (size_t)(b*NN)*NH + cw;
      #pragma unroll
      for (int mt=0;mt<13;mt++){
        #pragma unroll
        for (int r=0;r<4;r++){
          int n = mt*16 + q*4 + r;
          if (n < NN){
            float v = (acc[mt][r] + s2v)*inv + b2v;
            v = v>0.f ? v : 0.f;
            ushort hb = bf16h(v);
            sxh[obase + (size_t)n*NH] = hb;
            sxl[obase + (size_t)n*NH] = bf16h(v - bf16f(hb));
          }
        }
      }
    }
  }
}

// ---------------- LSTM v15 (r17 best, ~200 us) ----------------
// lstm12 structure (zero-unpack x hi/lo planes, depth-2 prefetch, packed-u32 h)
// at launch_bounds(256,2): mild spill accepted to keep 2 blocks/CU co-resident.
#define HS 68

__global__ __launch_bounds__(256, 2) void lstm15_kernel(
    const ushort* __restrict__ sxh, const ushort* __restrict__ sxl,
    const float* __restrict__ Wih, const float* __restrict__ Whh,
    const float* __restrict__ bih, const float* __restrict__ bhh,
    const float* __restrict__ Wfc, const float* __restrict__ bfc, float* __restrict__ out)
{
  __shared__ uint hf[2][16*HS + 4];    // 8.7 KB

  const int tid = threadIdx.x;
  const int l = tid & 63;
  const int w = __builtin_amdgcn_readfirstlane(tid >> 6);
  const int col = l & 15, q = l >> 4;
  const int g = blockIdx.x;

  // B fragments: [ty][mat*2+kk]; mat 0 = Wih (x), 1 = Whh (h). 128 VGPRs.
  bf8_t Bh[4][4], Bl[4][4];
  #pragma unroll
  for (int mat=0; mat<2; mat++){
    const float* W = mat ? Whh : Wih;
    #pragma unroll
    for (int ty=0; ty<4; ty++){
      #pragma unroll
      for (int kk=0; kk<2; kk++){
        const float* wp = W + (size_t)(ty*64 + w*16 + col)*64 + kk*32 + q*8;
        bf8_t ph, pl;
        #pragma unroll
        for (int j=0;j<8;j++){
          float wv = wp[j];
          ushort hb = bf16h(wv);
          ph[j] = (short)hb;
          pl[j] = (short)bf16h(wv - bf16f(hb));
        }
        Bh[ty][mat*2+kk] = ph;
        Bl[ty][mat*2+kk] = pl;
      }
    }
  }
  float bias[4];
  #pragma unroll
  for (int ty=0;ty<4;ty++){
    int r = ty*64 + w*16 + col;
    bias[ty] = bih[r] + bhh[r];
  }
  float c[4];
  #pragma unroll
  for (int i=0;i<4;i++) c[i]=0.f;

  for (int i=tid; i<16*HS; i+=256) hf[0][i] = 0;

  // x source: lane (col,q) reads 8 consecutive bf16 at row col, k = kk*32+q*8
  const ushort* xgh = sxh + (size_t)g*1024 + (size_t)(col*64 + q*8);
  const ushort* xgl = sxl + (size_t)g*1024 + (size_t)(col*64 + q*8);

  // depth-2 prefetch ring: slot (t&1) holds x(t)
  bf8_t pxh[2][2], pxl[2][2];
  #pragma unroll
  for (int s2=0; s2<2; s2++){
    const size_t off = (size_t)s2*TSU;
    pxh[s2][0] = *(const bf8_t*)(xgh + off);
    pxh[s2][1] = *(const bf8_t*)(xgh + off + 32);
    pxl[s2][0] = *(const bf8_t*)(xgl + off);
    pxl[s2][1] = *(const bf8_t*)(xgl + off + 32);
  }

  const int d = w*16 + col;
  const uint* hrd = &hf[0][0] + col*HS + q*8;
  __syncthreads();

  #pragma unroll 2
  for (int t=0; t<NT; t++){
    const int cur = t & 1;
    bf8_t cxh0 = pxh[cur][0], cxh1 = pxh[cur][1];
    bf8_t cxl0 = pxl[cur][0], cxl1 = pxl[cur][1];
    if (t+2 < NT){
      const size_t off = (size_t)(t+2)*TSU;
      pxh[cur][0] = *(const bf8_t*)(xgh + off);
      pxh[cur][1] = *(const bf8_t*)(xgh + off + 32);
      pxl[cur][0] = *(const bf8_t*)(xgl + off);
      pxl[cur][1] = *(const bf8_t*)(xgl + off + 32);
    }

    bf8_t hh[2], hl[2];
    {
      const uint* hb = hrd + (cur ? (16*HS+4) : 0);
      uint4 h0 = *(const uint4*)(hb);
      uint4 h1 = *(const uint4*)(hb + 4);
      uint4 h2 = *(const uint4*)(hb + 32);
      uint4 h3 = *(const uint4*)(hb + 36);
      uint u[8];
      u[0]=h0.x;u[1]=h0.y;u[2]=h0.z;u[3]=h0.w;u[4]=h1.x;u[5]=h1.y;u[6]=h1.z;u[7]=h1.w;
      #pragma unroll
      for (int j=0;j<8;j++){ hh[0][j]=(short)(u[j]>>16); hl[0][j]=(short)(u[j]&0xffff); }
      u[0]=h2.x;u[1]=h2.y;u[2]=h2.z;u[3]=h2.w;u[4]=h3.x;u[5]=h3.y;u[6]=h3.z;u[7]=h3.w;
      #pragma unroll
      for (int j=0;j<8;j++){ hh[1][j]=(short)(u[j]>>16); hl[1][j]=(short)(u[j]&0xffff); }
    }

    f4_t acc[4];
    #pragma unroll
    for (int ty=0;ty<4;ty++){ f4_t z; z[0]=bias[ty];z[1]=bias[ty];z[2]=bias[ty];z[3]=bias[ty]; acc[ty]=z; }
    #pragma unroll
    for (int ty=0;ty<4;ty++){
      acc[ty] = __builtin_amdgcn_mfma_f32_16x16x32_bf16(cxh0,  Bh[ty][0], acc[ty], 0,0,0);
      acc[ty] = __builtin_amdgcn_mfma_f32_16x16x32_bf16(cxl0,  Bh[ty][0], acc[ty], 0,0,0);
      acc[ty] = __builtin_amdgcn_mfma_f32_16x16x32_bf16(cxh0,  Bl[ty][0], acc[ty], 0,0,0);
      acc[ty] = __builtin_amdgcn_mfma_f32_16x16x32_bf16(cxh1,  Bh[ty][1], acc[ty], 0,0,0);
      acc[ty] = __builtin_amdgcn_mfma_f32_16x16x32_bf16(cxl1,  Bh[ty][1], acc[ty], 0,0,0);
      acc[ty] = __builtin_amdgcn_mfma_f32_16x16x32_bf16(cxh1,  Bl[ty][1], acc[ty], 0,0,0);
      acc[ty] = __builtin_amdgcn_mfma_f32_16x16x32_bf16(hh[0], Bh[ty][2], acc[ty], 0,0,0);
      acc[ty] = __builtin_amdgcn_mfma_f32_16x16x32_bf16(hl[0], Bh[ty][2], acc[ty], 0,0,0);
      acc[ty] = __builtin_amdgcn_mfma_f32_16x16x32_bf16(hh[0], Bl[ty][2], acc[ty], 0,0,0);
      acc[ty] = __builtin_amdgcn_mfma_f32_16x16x32_bf16(hh[1], Bh[ty][3], acc[ty], 0,0,0);
      acc[ty] = __builtin_amdgcn_mfma_f32_16x16x32_bf16(hl[1], Bh[ty][3], acc[ty], 0,0,0);
      acc[ty] = __builtin_amdgcn_mfma_f32_16x16x32_bf16(hh[1], Bl[ty][3], acc[ty], 0,0,0);
    }

    {
      uint* hw = &hf[cur^1][0];
      #pragma unroll
      for (int r=0;r<4;r++){
        float ig = fsig(acc[0][r]);
        float fg = fsig(acc[1][r]);
        float gt = ftanh(acc[2][r]);
        float og = fsig(acc[3][r]);
        float cc = fg*c[r] + ig*gt;
        c[r] = cc;
        float hv = og*ftanh(cc);
        int off = (q*4+r)*HS + d;
        if (t != NT-1){
          ushort hb2 = bf16h(hv);
          ushort lb2 = bf16h(hv - bf16f(hb2));
          hw[off] = ((uint)hb2<<16) | (uint)lb2;
        } else {
          hw[off] = __float_as_uint(hv);
        }
      }
    }
    __syncthreads();
  }

  if (tid < 16){
    float a = bfc[0];
    const uint* hT = &hf[NT&1][0];
    #pragma unroll 8
    for (int k=0;k<64;k++) a += __uint_as_float(hT[tid*HS + k]) * Wfc[k];
    out[g*16 + tid] = a;
  }
}

extern "C" void kernel_launch(void* const* d_in, const int* in_sizes, int n_in,
                              void* d_out, int out_size, void* d_ws, size_t ws_size,
                              hipStream_t stream) {
  const float* x   = (const float*)d_in[0];
  // d_in[1], d_in[2] (N1, N2): structurally dead — sigmoid(N1@N2)>0 is all-ones.
  const float* W1  = (const float*)d_in[3];
  const float* b1  = (const float*)d_in[4];
  const float* W2  = (const float*)d_in[5];
  const float* b2  = (const float*)d_in[6];
  const float* Wih = (const float*)d_in[7];
  const float* Whh = (const float*)d_in[8];
  const float* bih = (const float*)d_in[9];
  const float* bhh = (const float*)d_in[10];
  const float* Wfc = (const float*)d_in[11];
  const float* bfc = (const float*)d_in[12];

  ushort* sxh = (ushort*)d_ws;                 // [48][13248][64] bf16 hi (81.4 MB)
  ushort* sxl = sxh + (size_t)NT*TSU;          // [48][13248][64] bf16 lo (81.4 MB)
  float*  out = (float*)d_out;

  hipFuncSetAttribute((const void*)gcn_kernel, hipFuncAttributeMaxDynamicSharedMemorySize, GCN7_LDS_BYTES);

  gcn_kernel<<<dim3(NT/6, NB), 256, GCN7_LDS_BYTES, stream>>>(x, W1, b1, W2, b2, sxh, sxl);
  lstm15_kernel<<<NG, 256, 0, stream>>>(sxh, sxl, Wih, Whh, bih, bhh, Wfc, bfc, out);
}